// Round 5
// baseline (543.626 us; speedup 1.0000x reference)
//
#include <hip/hip_runtime.h>

typedef unsigned short u16;
typedef unsigned int   u32;

using bf16x8 = __attribute__((ext_vector_type(8))) short;
using f32x4  = __attribute__((ext_vector_type(4))) float;

#define MFMA16(A, B, C) __builtin_amdgcn_mfma_f32_16x16x32_bf16((A), (B), (C), 0, 0, 0)

static __device__ __forceinline__ u16 f2b(float f) {            // RNE
    u32 u = __builtin_bit_cast(u32, f);
    u32 r = (u + 0x7FFFu + ((u >> 16) & 1u)) >> 16;
    return (u16)r;
}
static __device__ __forceinline__ u16 f2bh(float f) {           // round-half-up
    u32 u = __builtin_bit_cast(u32, f) + 0x8000u;
    return (u16)(u >> 16);
}
// pack two floats -> two bf16 (half-up), a -> low16
static __device__ __forceinline__ u32 pk2(float fa, float fb) {
    u32 a = __builtin_bit_cast(u32, fa) + 0x8000u;
    u32 b = __builtin_bit_cast(u32, fb) + 0x8000u;
    return __builtin_amdgcn_perm(b, a, 0x07060302u);
}
static __device__ __forceinline__ bf16x8 cvt8f(f32x4 a, f32x4 b) {
    union { u32 w[4]; bf16x8 v; } r;
    r.w[0] = pk2(a[0], a[1]); r.w[1] = pk2(a[2], a[3]);
    r.w[2] = pk2(b[0], b[1]); r.w[3] = pk2(b[2], b[3]);
    return r.v;
}
static __device__ __forceinline__ bf16x8 cvt8(f32x4 a, f32x4 b) {   // RNE
    bf16x8 r;
    r[0] = (short)f2b(a[0]); r[1] = (short)f2b(a[1]);
    r[2] = (short)f2b(a[2]); r[3] = (short)f2b(a[3]);
    r[4] = (short)f2b(b[0]); r[5] = (short)f2b(b[1]);
    r[6] = (short)f2b(b[2]); r[7] = (short)f2b(b[3]);
    return r;
}

// ---------------------------------------------------------------------------
// K0: weight prep (fp32 -> bf16), unchanged.
__global__ __launch_bounds__(256) void k0_prep(
    const float* __restrict__ Wq, const float* __restrict__ Wk,
    const float* __restrict__ Wv, const float* __restrict__ Wres,
    const float* __restrict__ W1, const float* __restrict__ W2,
    u16* __restrict__ WcatT, u16* __restrict__ WresT,
    u16* __restrict__ WvT, u16* __restrict__ W1T, u16* __restrict__ W2T)
{
    int t = blockIdx.x * 256 + threadIdx.x;
    if (t < 131072) {
        int n = t >> 7, i = t & 127;
        int h = n >> 8, c = n & 255;
        const float* wq = Wq + i * 256 + h * 64;
        const float* wk = Wk + c * 256 + h * 64;
        float acc = 0.f;
        #pragma unroll 8
        for (int d = 0; d < 64; ++d) acc += wq[d] * wk[d];
        WcatT[t] = f2b(acc * 0.125f);
    } else if (t < 163840) {
        int o = t - 131072; int n = o >> 7, i = o & 127;
        WresT[o] = f2b(Wres[i * 256 + n]);
    } else if (t < 229376) {
        int o = t - 163840; int n = o >> 8, c = o & 255;
        WvT[o] = f2b(Wv[c * 256 + n]);
    } else if (t < 294912) {
        int o = t - 229376; int n = o >> 8, c = o & 255;
        W1T[o] = f2b(W1[c * 256 + n]);
    } else {
        int o = t - 294912; int n = o >> 8, c = o & 255;
        W2T[o] = f2b(W2[c * 256 + n]);
    }
}

// ---------------------------------------------------------------------------
// KF: fused qkvec-GEMM + attention + epilogue. 16 batch rows per block,
// 512 threads (8 waves), LDS 39552 B -> 4 blocks/CU = 32 waves/CU.
//
// __launch_bounds__(512, 8): 64-reg TOTAL budget (VGPR+AGPR unified on
// gfx950 — rocprof's VGPR_Count excludes AGPRs; R3/R4 showed reported
// 32/64 = half the real footprint). To fit 64 total WITHOUT the R3 spills,
// P2 is restructured for minimal live registers:
//   - freq/phase NOT hoisted (were 32 held VGPRs): re-loaded per use, L1-hit.
//   - te trig computed one MFMA-operand at a time (z8 -> sin -> MFMA ->
//     cos-from-same-z -> MFMA): peak trig live ~16 regs, was ~48.
//   - ltj shuffles moved after softmax (PV-local liveness).
//   - P1 unroll 4 -> 2 (halves concurrent accumulators).
// P2 has no block barrier in the i-loop (all LDS wave-private).
__global__ __launch_bounds__(512, 8) void kf_fused(
    const float* __restrict__ xu, const float* __restrict__ x_ctx,
    const float* __restrict__ t_ctx, const float* __restrict__ freq,
    const float* __restrict__ phase,
    const u16* __restrict__ WcatT, const u16* __restrict__ WvT,
    const u16* __restrict__ WresT, const u16* __restrict__ W1T,
    const u16* __restrict__ W2T,
    const float* __restrict__ bres, const float* __restrict__ b1,
    const float* __restrict__ b2, const float* __restrict__ g1,
    const float* __restrict__ be1, const float* __restrict__ g2,
    const float* __restrict__ be2, float* __restrict__ out)
{
    // layout:
    //   [    0,33024) kv[16][1032]  (u16)
    //   [33024,37376) xus[16][136]  (u16)
    //   [37376,39424) pw[8][4][32]  (u16)  | aliased by red[16][16][2] f32 (P3)
    //   [39424,39552) mrstd[16][2]  (f32)
    // P3 aliases of kv/xus region (xus dead once h1b/obuf tails reach it):
    //   zbuf[16][264] f32 @0      (16896)
    //   z1b [16][264] u16 @16896  (8448)
    //   h1b [16][264] u16 @25344  (8448, tail 768B into xus)
    //   obuf[16][264] f32 @16896  (16896)
    __shared__ __align__(16) char smem[39552];
    u16  (*kv)[1032]   = reinterpret_cast<u16 (*)[1032]>(smem);
    u16  (*xus)[136]   = reinterpret_cast<u16 (*)[136]>(smem + 33024);
    u16  (*pw)[4][32]  = reinterpret_cast<u16 (*)[4][32]>(smem + 37376);
    float(*red)[16][2] = reinterpret_cast<float (*)[16][2]>(smem + 37376); // alias pw
    float(*mrstd)[2]   = reinterpret_cast<float (*)[2]>(smem + 39424);
    float(*zbuf)[264]  = reinterpret_cast<float (*)[264]>(smem);           // alias kv
    u16  (*z1b)[264]   = reinterpret_cast<u16 (*)[264]>(smem + 16896);
    u16  (*h1b)[264]   = reinterpret_cast<u16 (*)[264]>(smem + 25344);
    float(*obuf)[264]  = reinterpret_cast<float (*)[264]>(smem + 16896);

    const int b0 = blockIdx.x * 16;
    const int t = threadIdx.x;
    const int lane = t & 63, wave = t >> 6;          // wave in [0,8)
    const int quad = lane >> 4, l16 = lane & 15;
    const int fb = quad * 8;
    const f32x4 zz = {0.f, 0.f, 0.f, 0.f};

    // ---- P0: stage x_u rows (bf16) ----
    if (t < 256) {
        int row = t >> 4, ch = t & 15;
        const float* src = xu + (size_t)(b0 + row) * 128 + ch * 8;
        *(bf16x8*)&xus[row][ch * 8] = cvt8(*(const f32x4*)src, *(const f32x4*)(src + 4));
    }
    __syncthreads();

    // ---- P1: kv[row][n] = qkvec = x_u @ Wcat (K=128); wave owns n-range w*128.. ----
    #pragma unroll 2
    for (int nt = 0; nt < 8; ++nt) {
        int n0 = wave * 128 + nt * 16;
        f32x4 acc = zz;
        #pragma unroll
        for (int ks = 0; ks < 4; ++ks) {
            bf16x8 afr = *(const bf16x8*)&xus[l16][ks * 32 + fb];
            bf16x8 bfr = *(const bf16x8*)(WcatT + (size_t)(n0 + l16) * 128 + ks * 32 + fb);
            acc = MFMA16(afr, bfr, acc);
        }
        #pragma unroll
        for (int r = 0; r < 4; ++r)
            kv[quad * 4 + r][n0 + l16] = f2b(acc[r]);
    }
    __syncthreads();

    // ---- P2: attention; wave w handles b = b0 + w*2 + i ----
    for (int i = 0; i < 2; ++i) {
        const int kvrow = wave * 2 + i;
        const int b = b0 + kvrow;
        float ltv = log1pf(fmaxf(t_ctx[(size_t)b * 32 + (lane & 31)], 0.f));
        const u16* qb = &kv[kvrow][(l16 & 3) * 256];

        // attT: D[l][h-replica], K=256
        f32x4 accA[2];
        #pragma unroll
        for (int ltile = 0; ltile < 2; ++ltile) {
            const float* xrow = x_ctx + ((size_t)b * 32 + ltile * 16 + l16) * 128;
            f32x4 acc = zz;
            #pragma unroll
            for (int ks = 0; ks < 4; ++ks) {
                f32x4 a = *(const f32x4*)(xrow + ks * 32 + fb);
                f32x4 c = *(const f32x4*)(xrow + ks * 32 + fb + 4);
                acc = MFMA16(cvt8f(a, c), *(const bf16x8*)(qb + ks * 32 + fb), acc);
            }
            float lt_l = __shfl(ltv, ltile * 16 + l16);
            // te part: one operand at a time; freq/phase loaded per use (L1).
            #pragma unroll
            for (int hf = 0; hf < 2; ++hf) {
                f32x4 fa = *(const f32x4*)(freq + hf * 32 + fb);
                f32x4 fc = *(const f32x4*)(freq + hf * 32 + fb + 4);
                f32x4 pa = *(const f32x4*)(phase + hf * 32 + fb);
                f32x4 pc = *(const f32x4*)(phase + hf * 32 + fb + 4);
                f32x4 za = fa * lt_l + pa;
                f32x4 zc = fc * lt_l + pc;
                f32x4 sa, sc;
                #pragma unroll
                for (int j = 0; j < 4; ++j) { sa[j] = __sinf(za[j]); sc[j] = __sinf(zc[j]); }
                acc = MFMA16(cvt8f(sa, sc), *(const bf16x8*)(qb + 128 + hf * 32 + fb), acc);
                #pragma unroll
                for (int j = 0; j < 4; ++j) { sa[j] = __cosf(za[j]); sc[j] = __cosf(zc[j]); }
                acc = MFMA16(cvt8f(sa, sc), *(const bf16x8*)(qb + 192 + hf * 32 + fb), acc);
            }
            accA[ltile] = acc;
        }

        // softmax over l
        float m = accA[0][0];
        #pragma unroll
        for (int r = 1; r < 4; ++r) m = fmaxf(m, accA[0][r]);
        #pragma unroll
        for (int r = 0; r < 4; ++r) m = fmaxf(m, accA[1][r]);
        m = fmaxf(m, __shfl_xor(m, 16));
        m = fmaxf(m, __shfl_xor(m, 32));
        float p[2][4], s = 0.f;
        #pragma unroll
        for (int lt2 = 0; lt2 < 2; ++lt2)
            #pragma unroll
            for (int r = 0; r < 4; ++r) { p[lt2][r] = __expf(accA[lt2][r] - m); s += p[lt2][r]; }
        s += __shfl_xor(s, 16);
        s += __shfl_xor(s, 32);
        float inv = 1.f / s;
        if (l16 < 4) {
            #pragma unroll
            for (int lt2 = 0; lt2 < 2; ++lt2)
                #pragma unroll
                for (int r = 0; r < 4; ++r)
                    pw[wave][l16][lt2 * 16 + quad * 4 + r] = f2bh(p[lt2][r] * inv);
        }
        // no block barrier: pw is wave-private; lgkmcnt orders write->read.

        // PV: ctx[h][c] overwrites kv[kvrow] in place (row fully consumed above)
        bf16x8 pfr = *(const bf16x8*)&pw[wave][l16 & 3][fb];

        #pragma unroll
        for (int nt = 0; nt < 8; ++nt) {
            int c = nt * 16 + l16;
            const float* xp = x_ctx + ((size_t)b * 32 + fb) * 128 + c;
            float v0 = xp[0], v1 = xp[128], v2 = xp[256], v3 = xp[384];
            float v4 = xp[512], v5 = xp[640], v6 = xp[768], v7 = xp[896];
            union { u32 w[4]; bf16x8 v; } bu;
            bu.w[0] = pk2(v0, v1); bu.w[1] = pk2(v2, v3);
            bu.w[2] = pk2(v4, v5); bu.w[3] = pk2(v6, v7);
            f32x4 d = MFMA16(pfr, bu.v, zz);
            if (quad == 0) {
                #pragma unroll
                for (int r = 0; r < 4; ++r) kv[kvrow][r * 256 + c] = f2bh(d[r]);
            }
        }
        float ltj[8];
        #pragma unroll
        for (int j = 0; j < 8; ++j) ltj[j] = __shfl(ltv, fb + j);
        #pragma unroll
        for (int pp = 0; pp < 4; ++pp) {
            int f = pp * 16 + l16;
            float fq = freq[f], phf = phase[f];
            float z8[8];
            #pragma unroll
            for (int j = 0; j < 8; ++j) z8[j] = ltj[j] * fq + phf;
            union { u32 w[4]; bf16x8 v; } bs, bc;
            #pragma unroll
            for (int j = 0; j < 4; ++j) {
                bs.w[j] = pk2(__sinf(z8[2 * j]), __sinf(z8[2 * j + 1]));
                bc.w[j] = pk2(__cosf(z8[2 * j]), __cosf(z8[2 * j + 1]));
            }
            f32x4 ds = MFMA16(pfr, bs.v, zz);
            f32x4 dc = MFMA16(pfr, bc.v, zz);
            if (quad == 0) {
                #pragma unroll
                for (int r = 0; r < 4; ++r) {
                    kv[kvrow][r * 256 + 128 + f] = f2bh(ds[r]);
                    kv[kvrow][r * 256 + 192 + f] = f2bh(dc[r]);
                }
            }
        }
    }
    __syncthreads();

    // ---- P3: epilogue. Wave owns 32 output cols; head = wave>>1. ----
    const int nw = wave * 32;
    const int hd = (wave >> 1) * 256;

    // Phase A: agg = ctx_head @ Wv + xu @ Wres + bres
    f32x4 acc[2];
    #pragma unroll
    for (int nt = 0; nt < 2; ++nt) acc[nt] = zz;
    #pragma unroll
    for (int ks = 0; ks < 8; ++ks) {
        bf16x8 afr = *(const bf16x8*)&kv[l16][hd + ks * 32 + quad * 8];
        #pragma unroll
        for (int nt = 0; nt < 2; ++nt) {
            bf16x8 bfr = *(const bf16x8*)(WvT + (size_t)(nw + nt * 16 + l16) * 256 + ks * 32 + quad * 8);
            acc[nt] = MFMA16(afr, bfr, acc[nt]);
        }
    }
    #pragma unroll
    for (int ks = 0; ks < 4; ++ks) {
        bf16x8 afr = *(const bf16x8*)&xus[l16][ks * 32 + quad * 8];
        #pragma unroll
        for (int nt = 0; nt < 2; ++nt) {
            bf16x8 bfr = *(const bf16x8*)(WresT + (size_t)(nw + nt * 16 + l16) * 128 + ks * 32 + quad * 8);
            acc[nt] = MFMA16(afr, bfr, acc[nt]);
        }
    }
    __syncthreads();                               // kv/xus dead
    #pragma unroll
    for (int nt = 0; nt < 2; ++nt) {
        int col = nw + nt * 16 + l16;
        float bb = bres[col];
        #pragma unroll
        for (int r = 0; r < 4; ++r)
            zbuf[quad * 4 + r][col] = acc[nt][r] + bb;
    }
    __syncthreads();

    // LN1
    if (t < 256) {
        int row = t >> 4, j = t & 15;
        float s = 0.f, s2 = 0.f;
        #pragma unroll
        for (int i2 = 0; i2 < 16; ++i2) { float v = zbuf[row][j + 16 * i2]; s += v; s2 += v * v; }
        red[row][j][0] = s; red[row][j][1] = s2;
    }
    __syncthreads();
    if (t < 16) {
        float s = 0.f, s2 = 0.f;
        #pragma unroll
        for (int j = 0; j < 16; ++j) { s += red[t][j][0]; s2 += red[t][j][1]; }
        float m = s * (1.f / 256.f);
        float var = s2 * (1.f / 256.f) - m * m;
        mrstd[t][0] = m;
        mrstd[t][1] = rsqrtf(var + 1e-5f);
    }
    __syncthreads();
    {
        int col = t & 255, rh = (t >> 8) * 8;
        float g = g1[col], be = be1[col];
        #pragma unroll
        for (int i2 = 0; i2 < 8; ++i2) {
            int row = rh + i2;
            float z = (zbuf[row][col] - mrstd[row][0]) * mrstd[row][1] * g + be;
            zbuf[row][col] = z;
            z1b[row][col] = f2b(z);
        }
    }
    __syncthreads();

    // Phase B: FFN1 + relu
    f32x4 acc2[2];
    #pragma unroll
    for (int nt = 0; nt < 2; ++nt) acc2[nt] = zz;
    #pragma unroll
    for (int ks = 0; ks < 8; ++ks) {
        bf16x8 afr = *(const bf16x8*)&z1b[l16][ks * 32 + quad * 8];
        #pragma unroll
        for (int nt = 0; nt < 2; ++nt) {
            bf16x8 bfr = *(const bf16x8*)(W1T + (size_t)(nw + nt * 16 + l16) * 256 + ks * 32 + quad * 8);
            acc2[nt] = MFMA16(afr, bfr, acc2[nt]);
        }
    }
    #pragma unroll
    for (int nt = 0; nt < 2; ++nt) {
        int col = nw + nt * 16 + l16;
        float bb = b1[col];
        #pragma unroll
        for (int r = 0; r < 4; ++r)
            h1b[quad * 4 + r][col] = f2b(fmaxf(acc2[nt][r] + bb, 0.f));
    }
    __syncthreads();

    // Phase C: FFN2 + residual
    f32x4 acc3[2];
    #pragma unroll
    for (int nt = 0; nt < 2; ++nt) acc3[nt] = zz;
    #pragma unroll
    for (int ks = 0; ks < 8; ++ks) {
        bf16x8 afr = *(const bf16x8*)&h1b[l16][ks * 32 + quad * 8];
        #pragma unroll
        for (int nt = 0; nt < 2; ++nt) {
            bf16x8 bfr = *(const bf16x8*)(W2T + (size_t)(nw + nt * 16 + l16) * 256 + ks * 32 + quad * 8);
            acc3[nt] = MFMA16(afr, bfr, acc3[nt]);
        }
    }
    __syncthreads();                               // z1b/h1b dead
    #pragma unroll
    for (int nt = 0; nt < 2; ++nt) {
        int col = nw + nt * 16 + l16;
        float bb = b2[col];
        #pragma unroll
        for (int r = 0; r < 4; ++r) {
            int row = quad * 4 + r;
            obuf[row][col] = acc3[nt][r] + bb + zbuf[row][col];
        }
    }
    __syncthreads();

    // LN2 + store (fp32)
    if (t < 256) {
        int row = t >> 4, j = t & 15;
        float s = 0.f, s2 = 0.f;
        #pragma unroll
        for (int i2 = 0; i2 < 16; ++i2) { float v = obuf[row][j + 16 * i2]; s += v; s2 += v * v; }
        red[row][j][0] = s; red[row][j][1] = s2;
    }
    __syncthreads();
    if (t < 16) {
        float s = 0.f, s2 = 0.f;
        #pragma unroll
        for (int j = 0; j < 16; ++j) { s += red[t][j][0]; s2 += red[t][j][1]; }
        float m = s * (1.f / 256.f);
        float var = s2 * (1.f / 256.f) - m * m;
        mrstd[t][0] = m;
        mrstd[t][1] = rsqrtf(var + 1e-5f);
    }
    __syncthreads();
    {
        int col = t & 255, rh = (t >> 8) * 8;
        float g = g2[col], be = be2[col];
        #pragma unroll
        for (int i2 = 0; i2 < 8; ++i2) {
            int row = rh + i2;
            out[(size_t)(b0 + row) * 256 + col] =
                (obuf[row][col] - mrstd[row][0]) * mrstd[row][1] * g + be;
        }
    }
}

// ---------------------------------------------------------------------------
extern "C" void kernel_launch(void* const* d_in, const int* in_sizes, int n_in,
                              void* d_out, int out_size, void* d_ws, size_t ws_size,
                              hipStream_t stream)
{
    (void)in_sizes; (void)n_in; (void)out_size; (void)ws_size;
    const float* xu    = (const float*)d_in[0];
    const float* x_ctx = (const float*)d_in[1];
    const float* t_ctx = (const float*)d_in[2];
    const float* freq  = (const float*)d_in[3];
    const float* phase = (const float*)d_in[4];
    const float* Wq    = (const float*)d_in[5];
    const float* Wk    = (const float*)d_in[6];
    const float* Wv    = (const float*)d_in[7];
    const float* Wres  = (const float*)d_in[8];
    const float* bres  = (const float*)d_in[9];
    const float* W1    = (const float*)d_in[10];
    const float* b1    = (const float*)d_in[11];
    const float* W2    = (const float*)d_in[12];
    const float* b2    = (const float*)d_in[13];
    const float* g1    = (const float*)d_in[14];
    const float* be1   = (const float*)d_in[15];
    const float* g2    = (const float*)d_in[16];
    const float* be2   = (const float*)d_in[17];
    float* out = (float*)d_out;

    char* ws = (char*)d_ws;
    u16* WcatT = (u16*)(ws);                    // 262,144 B
    u16* WresT = (u16*)(ws + 262144);           //  65,536
    u16* WvT   = (u16*)(ws + 327680);           // 131,072
    u16* W1T   = (u16*)(ws + 458752);           // 131,072
    u16* W2T   = (u16*)(ws + 589824);           // 131,072  (total 720,896 B)

    hipLaunchKernelGGL(k0_prep, dim3(1408), dim3(256), 0, stream,
                       Wq, Wk, Wv, Wres, W1, W2, WcatT, WresT, WvT, W1T, W2T);
    hipLaunchKernelGGL(kf_fused, dim3(1024), dim3(512), 0, stream,
                       xu, x_ctx, t_ctx, freq, phase,
                       WcatT, WvT, WresT, W1T, W2T,
                       bres, b1, b2, g1, be1, g2, be2, out);
}

// Round 6
// 530.844 us; speedup vs baseline: 1.0241x; 1.0241x over previous
//
#include <hip/hip_runtime.h>

typedef unsigned short u16;
typedef unsigned int   u32;

using bf16x8 = __attribute__((ext_vector_type(8))) short;
using f32x4  = __attribute__((ext_vector_type(4))) float;

#define MFMA16(A, B, C) __builtin_amdgcn_mfma_f32_16x16x32_bf16((A), (B), (C), 0, 0, 0)

static __device__ __forceinline__ u16 f2b(float f) {            // RNE
    u32 u = __builtin_bit_cast(u32, f);
    u32 r = (u + 0x7FFFu + ((u >> 16) & 1u)) >> 16;
    return (u16)r;
}
static __device__ __forceinline__ u16 f2bh(float f) {           // round-half-up
    u32 u = __builtin_bit_cast(u32, f) + 0x8000u;
    return (u16)(u >> 16);
}
// pack two floats -> two bf16 (half-up), a -> low16
static __device__ __forceinline__ u32 pk2(float fa, float fb) {
    u32 a = __builtin_bit_cast(u32, fa) + 0x8000u;
    u32 b = __builtin_bit_cast(u32, fb) + 0x8000u;
    return __builtin_amdgcn_perm(b, a, 0x07060302u);
}
static __device__ __forceinline__ bf16x8 cvt8f(f32x4 a, f32x4 b) {
    union { u32 w[4]; bf16x8 v; } r;
    r.w[0] = pk2(a[0], a[1]); r.w[1] = pk2(a[2], a[3]);
    r.w[2] = pk2(b[0], b[1]); r.w[3] = pk2(b[2], b[3]);
    return r.v;
}
static __device__ __forceinline__ bf16x8 cvt8(f32x4 a, f32x4 b) {   // RNE
    bf16x8 r;
    r[0] = (short)f2b(a[0]); r[1] = (short)f2b(a[1]);
    r[2] = (short)f2b(a[2]); r[3] = (short)f2b(a[3]);
    r[4] = (short)f2b(b[0]); r[5] = (short)f2b(b[1]);
    r[6] = (short)f2b(b[2]); r[7] = (short)f2b(b[3]);
    return r;
}

// ---------------------------------------------------------------------------
// K0: weight prep (fp32 -> bf16), unchanged.
__global__ __launch_bounds__(256) void k0_prep(
    const float* __restrict__ Wq, const float* __restrict__ Wk,
    const float* __restrict__ Wv, const float* __restrict__ Wres,
    const float* __restrict__ W1, const float* __restrict__ W2,
    u16* __restrict__ WcatT, u16* __restrict__ WresT,
    u16* __restrict__ WvT, u16* __restrict__ W1T, u16* __restrict__ W2T)
{
    int t = blockIdx.x * 256 + threadIdx.x;
    if (t < 131072) {
        int n = t >> 7, i = t & 127;
        int h = n >> 8, c = n & 255;
        const float* wq = Wq + i * 256 + h * 64;
        const float* wk = Wk + c * 256 + h * 64;
        float acc = 0.f;
        #pragma unroll 8
        for (int d = 0; d < 64; ++d) acc += wq[d] * wk[d];
        WcatT[t] = f2b(acc * 0.125f);
    } else if (t < 163840) {
        int o = t - 131072; int n = o >> 7, i = o & 127;
        WresT[o] = f2b(Wres[i * 256 + n]);
    } else if (t < 229376) {
        int o = t - 163840; int n = o >> 8, c = o & 255;
        WvT[o] = f2b(Wv[c * 256 + n]);
    } else if (t < 294912) {
        int o = t - 229376; int n = o >> 8, c = o & 255;
        W1T[o] = f2b(W1[c * 256 + n]);
    } else {
        int o = t - 294912; int n = o >> 8, c = o & 255;
        W2T[o] = f2b(W2[c * 256 + n]);
    }
}

// ---------------------------------------------------------------------------
// KF: fused qkvec-GEMM + attention + epilogue. 16 batch rows per block,
// 512 threads (8 waves), LDS 39552 B.
//
// Register-tier ladder measured so far (512-thr blocks -> 2 waves/SIMD each,
// so resident tiers are 4/6/8 waves per SIMD = 2/3/4 blocks per CU):
//   (512,4): 128-reg budget -> clean (no spill), 16 waves/CU, 201 us
//   (512,8):  64-reg budget -> ~30 dwords/thread spilled, 32 waves/CU, 246 us
// => true live-set is between 64 and ~100. This round: (512,6) = 85-reg
// budget, the intermediate tier: 3 blocks/CU = 24 waves/CU if it fits.
// Verification bit: WRITE_SIZE ~16 MB means spill-free; >50 MB means the
// tier chase is dead and P2 gets split into its own kernel next.
//
// P2 liveness trims (from R5, kept): freq/phase loaded per use (not hoisted);
// te trig one MFMA-operand at a time; ltj after softmax; P1 unroll 2.
// New this round: PV trig drops z8[8] (z recomputed in the cos pass).
__global__ __launch_bounds__(512, 6) void kf_fused(
    const float* __restrict__ xu, const float* __restrict__ x_ctx,
    const float* __restrict__ t_ctx, const float* __restrict__ freq,
    const float* __restrict__ phase,
    const u16* __restrict__ WcatT, const u16* __restrict__ WvT,
    const u16* __restrict__ WresT, const u16* __restrict__ W1T,
    const u16* __restrict__ W2T,
    const float* __restrict__ bres, const float* __restrict__ b1,
    const float* __restrict__ b2, const float* __restrict__ g1,
    const float* __restrict__ be1, const float* __restrict__ g2,
    const float* __restrict__ be2, float* __restrict__ out)
{
    // layout:
    //   [    0,33024) kv[16][1032]  (u16)
    //   [33024,37376) xus[16][136]  (u16)
    //   [37376,39424) pw[8][4][32]  (u16)  | aliased by red[16][16][2] f32 (P3)
    //   [39424,39552) mrstd[16][2]  (f32)
    // P3 aliases of kv/xus region (xus dead once h1b/obuf tails reach it):
    //   zbuf[16][264] f32 @0      (16896)
    //   z1b [16][264] u16 @16896  (8448)
    //   h1b [16][264] u16 @25344  (8448, tail 768B into xus)
    //   obuf[16][264] f32 @16896  (16896)
    __shared__ __align__(16) char smem[39552];
    u16  (*kv)[1032]   = reinterpret_cast<u16 (*)[1032]>(smem);
    u16  (*xus)[136]   = reinterpret_cast<u16 (*)[136]>(smem + 33024);
    u16  (*pw)[4][32]  = reinterpret_cast<u16 (*)[4][32]>(smem + 37376);
    float(*red)[16][2] = reinterpret_cast<float (*)[16][2]>(smem + 37376); // alias pw
    float(*mrstd)[2]   = reinterpret_cast<float (*)[2]>(smem + 39424);
    float(*zbuf)[264]  = reinterpret_cast<float (*)[264]>(smem);           // alias kv
    u16  (*z1b)[264]   = reinterpret_cast<u16 (*)[264]>(smem + 16896);
    u16  (*h1b)[264]   = reinterpret_cast<u16 (*)[264]>(smem + 25344);
    float(*obuf)[264]  = reinterpret_cast<float (*)[264]>(smem + 16896);

    const int b0 = blockIdx.x * 16;
    const int t = threadIdx.x;
    const int lane = t & 63, wave = t >> 6;          // wave in [0,8)
    const int quad = lane >> 4, l16 = lane & 15;
    const int fb = quad * 8;
    const f32x4 zz = {0.f, 0.f, 0.f, 0.f};

    // ---- P0: stage x_u rows (bf16) ----
    if (t < 256) {
        int row = t >> 4, ch = t & 15;
        const float* src = xu + (size_t)(b0 + row) * 128 + ch * 8;
        *(bf16x8*)&xus[row][ch * 8] = cvt8(*(const f32x4*)src, *(const f32x4*)(src + 4));
    }
    __syncthreads();

    // ---- P1: kv[row][n] = qkvec = x_u @ Wcat (K=128); wave owns n-range w*128.. ----
    #pragma unroll 2
    for (int nt = 0; nt < 8; ++nt) {
        int n0 = wave * 128 + nt * 16;
        f32x4 acc = zz;
        #pragma unroll
        for (int ks = 0; ks < 4; ++ks) {
            bf16x8 afr = *(const bf16x8*)&xus[l16][ks * 32 + fb];
            bf16x8 bfr = *(const bf16x8*)(WcatT + (size_t)(n0 + l16) * 128 + ks * 32 + fb);
            acc = MFMA16(afr, bfr, acc);
        }
        #pragma unroll
        for (int r = 0; r < 4; ++r)
            kv[quad * 4 + r][n0 + l16] = f2b(acc[r]);
    }
    __syncthreads();

    // ---- P2: attention; wave w handles b = b0 + w*2 + i ----
    for (int i = 0; i < 2; ++i) {
        const int kvrow = wave * 2 + i;
        const int b = b0 + kvrow;
        float ltv = log1pf(fmaxf(t_ctx[(size_t)b * 32 + (lane & 31)], 0.f));
        const u16* qb = &kv[kvrow][(l16 & 3) * 256];

        // attT: D[l][h-replica], K=256
        f32x4 accA[2];
        #pragma unroll
        for (int ltile = 0; ltile < 2; ++ltile) {
            const float* xrow = x_ctx + ((size_t)b * 32 + ltile * 16 + l16) * 128;
            f32x4 acc = zz;
            #pragma unroll
            for (int ks = 0; ks < 4; ++ks) {
                f32x4 a = *(const f32x4*)(xrow + ks * 32 + fb);
                f32x4 c = *(const f32x4*)(xrow + ks * 32 + fb + 4);
                acc = MFMA16(cvt8f(a, c), *(const bf16x8*)(qb + ks * 32 + fb), acc);
            }
            float lt_l = __shfl(ltv, ltile * 16 + l16);
            // te part: one operand at a time; freq/phase loaded per use (L1).
            #pragma unroll
            for (int hf = 0; hf < 2; ++hf) {
                f32x4 fa = *(const f32x4*)(freq + hf * 32 + fb);
                f32x4 fc = *(const f32x4*)(freq + hf * 32 + fb + 4);
                f32x4 pa = *(const f32x4*)(phase + hf * 32 + fb);
                f32x4 pc = *(const f32x4*)(phase + hf * 32 + fb + 4);
                f32x4 za = fa * lt_l + pa;
                f32x4 zc = fc * lt_l + pc;
                f32x4 sa, sc;
                #pragma unroll
                for (int j = 0; j < 4; ++j) { sa[j] = __sinf(za[j]); sc[j] = __sinf(zc[j]); }
                acc = MFMA16(cvt8f(sa, sc), *(const bf16x8*)(qb + 128 + hf * 32 + fb), acc);
                #pragma unroll
                for (int j = 0; j < 4; ++j) { sa[j] = __cosf(za[j]); sc[j] = __cosf(zc[j]); }
                acc = MFMA16(cvt8f(sa, sc), *(const bf16x8*)(qb + 192 + hf * 32 + fb), acc);
            }
            accA[ltile] = acc;
        }

        // softmax over l
        float m = accA[0][0];
        #pragma unroll
        for (int r = 1; r < 4; ++r) m = fmaxf(m, accA[0][r]);
        #pragma unroll
        for (int r = 0; r < 4; ++r) m = fmaxf(m, accA[1][r]);
        m = fmaxf(m, __shfl_xor(m, 16));
        m = fmaxf(m, __shfl_xor(m, 32));
        float p[2][4], s = 0.f;
        #pragma unroll
        for (int lt2 = 0; lt2 < 2; ++lt2)
            #pragma unroll
            for (int r = 0; r < 4; ++r) { p[lt2][r] = __expf(accA[lt2][r] - m); s += p[lt2][r]; }
        s += __shfl_xor(s, 16);
        s += __shfl_xor(s, 32);
        float inv = 1.f / s;
        if (l16 < 4) {
            #pragma unroll
            for (int lt2 = 0; lt2 < 2; ++lt2)
                #pragma unroll
                for (int r = 0; r < 4; ++r)
                    pw[wave][l16][lt2 * 16 + quad * 4 + r] = f2bh(p[lt2][r] * inv);
        }
        // no block barrier: pw is wave-private; lgkmcnt orders write->read.

        // PV: ctx[h][c] overwrites kv[kvrow] in place (row fully consumed above)
        bf16x8 pfr = *(const bf16x8*)&pw[wave][l16 & 3][fb];

        #pragma unroll
        for (int nt = 0; nt < 8; ++nt) {
            int c = nt * 16 + l16;
            const float* xp = x_ctx + ((size_t)b * 32 + fb) * 128 + c;
            float v0 = xp[0], v1 = xp[128], v2 = xp[256], v3 = xp[384];
            float v4 = xp[512], v5 = xp[640], v6 = xp[768], v7 = xp[896];
            union { u32 w[4]; bf16x8 v; } bu;
            bu.w[0] = pk2(v0, v1); bu.w[1] = pk2(v2, v3);
            bu.w[2] = pk2(v4, v5); bu.w[3] = pk2(v6, v7);
            f32x4 d = MFMA16(pfr, bu.v, zz);
            if (quad == 0) {
                #pragma unroll
                for (int r = 0; r < 4; ++r) kv[kvrow][r * 256 + c] = f2bh(d[r]);
            }
        }
        float ltj[8];
        #pragma unroll
        for (int j = 0; j < 8; ++j) ltj[j] = __shfl(ltv, fb + j);
        #pragma unroll
        for (int pp = 0; pp < 4; ++pp) {
            int f = pp * 16 + l16;
            float fq = freq[f], phf = phase[f];
            union { u32 w[4]; bf16x8 v; } bs, bc;
            #pragma unroll
            for (int j = 0; j < 4; ++j) {
                float za = ltj[2 * j] * fq + phf;
                float zb = ltj[2 * j + 1] * fq + phf;
                bs.w[j] = pk2(__sinf(za), __sinf(zb));
                bc.w[j] = pk2(__cosf(za), __cosf(zb));
            }
            f32x4 ds = MFMA16(pfr, bs.v, zz);
            f32x4 dc = MFMA16(pfr, bc.v, zz);
            if (quad == 0) {
                #pragma unroll
                for (int r = 0; r < 4; ++r) {
                    kv[kvrow][r * 256 + 128 + f] = f2bh(ds[r]);
                    kv[kvrow][r * 256 + 192 + f] = f2bh(dc[r]);
                }
            }
        }
    }
    __syncthreads();

    // ---- P3: epilogue. Wave owns 32 output cols; head = wave>>1. ----
    const int nw = wave * 32;
    const int hd = (wave >> 1) * 256;

    // Phase A: agg = ctx_head @ Wv + xu @ Wres + bres
    f32x4 acc[2];
    #pragma unroll
    for (int nt = 0; nt < 2; ++nt) acc[nt] = zz;
    #pragma unroll
    for (int ks = 0; ks < 8; ++ks) {
        bf16x8 afr = *(const bf16x8*)&kv[l16][hd + ks * 32 + quad * 8];
        #pragma unroll
        for (int nt = 0; nt < 2; ++nt) {
            bf16x8 bfr = *(const bf16x8*)(WvT + (size_t)(nw + nt * 16 + l16) * 256 + ks * 32 + quad * 8);
            acc[nt] = MFMA16(afr, bfr, acc[nt]);
        }
    }
    #pragma unroll
    for (int ks = 0; ks < 4; ++ks) {
        bf16x8 afr = *(const bf16x8*)&xus[l16][ks * 32 + quad * 8];
        #pragma unroll
        for (int nt = 0; nt < 2; ++nt) {
            bf16x8 bfr = *(const bf16x8*)(WresT + (size_t)(nw + nt * 16 + l16) * 128 + ks * 32 + quad * 8);
            acc[nt] = MFMA16(afr, bfr, acc[nt]);
        }
    }
    __syncthreads();                               // kv/xus dead
    #pragma unroll
    for (int nt = 0; nt < 2; ++nt) {
        int col = nw + nt * 16 + l16;
        float bb = bres[col];
        #pragma unroll
        for (int r = 0; r < 4; ++r)
            zbuf[quad * 4 + r][col] = acc[nt][r] + bb;
    }
    __syncthreads();

    // LN1
    if (t < 256) {
        int row = t >> 4, j = t & 15;
        float s = 0.f, s2 = 0.f;
        #pragma unroll
        for (int i2 = 0; i2 < 16; ++i2) { float v = zbuf[row][j + 16 * i2]; s += v; s2 += v * v; }
        red[row][j][0] = s; red[row][j][1] = s2;
    }
    __syncthreads();
    if (t < 16) {
        float s = 0.f, s2 = 0.f;
        #pragma unroll
        for (int j = 0; j < 16; ++j) { s += red[t][j][0]; s2 += red[t][j][1]; }
        float m = s * (1.f / 256.f);
        float var = s2 * (1.f / 256.f) - m * m;
        mrstd[t][0] = m;
        mrstd[t][1] = rsqrtf(var + 1e-5f);
    }
    __syncthreads();
    {
        int col = t & 255, rh = (t >> 8) * 8;
        float g = g1[col], be = be1[col];
        #pragma unroll
        for (int i2 = 0; i2 < 8; ++i2) {
            int row = rh + i2;
            float z = (zbuf[row][col] - mrstd[row][0]) * mrstd[row][1] * g + be;
            zbuf[row][col] = z;
            z1b[row][col] = f2b(z);
        }
    }
    __syncthreads();

    // Phase B: FFN1 + relu
    f32x4 acc2[2];
    #pragma unroll
    for (int nt = 0; nt < 2; ++nt) acc2[nt] = zz;
    #pragma unroll
    for (int ks = 0; ks < 8; ++ks) {
        bf16x8 afr = *(const bf16x8*)&z1b[l16][ks * 32 + quad * 8];
        #pragma unroll
        for (int nt = 0; nt < 2; ++nt) {
            bf16x8 bfr = *(const bf16x8*)(W1T + (size_t)(nw + nt * 16 + l16) * 256 + ks * 32 + quad * 8);
            acc2[nt] = MFMA16(afr, bfr, acc2[nt]);
        }
    }
    #pragma unroll
    for (int nt = 0; nt < 2; ++nt) {
        int col = nw + nt * 16 + l16;
        float bb = b1[col];
        #pragma unroll
        for (int r = 0; r < 4; ++r)
            h1b[quad * 4 + r][col] = f2b(fmaxf(acc2[nt][r] + bb, 0.f));
    }
    __syncthreads();

    // Phase C: FFN2 + residual
    f32x4 acc3[2];
    #pragma unroll
    for (int nt = 0; nt < 2; ++nt) acc3[nt] = zz;
    #pragma unroll
    for (int ks = 0; ks < 8; ++ks) {
        bf16x8 afr = *(const bf16x8*)&h1b[l16][ks * 32 + quad * 8];
        #pragma unroll
        for (int nt = 0; nt < 2; ++nt) {
            bf16x8 bfr = *(const bf16x8*)(W2T + (size_t)(nw + nt * 16 + l16) * 256 + ks * 32 + quad * 8);
            acc3[nt] = MFMA16(afr, bfr, acc3[nt]);
        }
    }
    __syncthreads();                               // z1b/h1b dead
    #pragma unroll
    for (int nt = 0; nt < 2; ++nt) {
        int col = nw + nt * 16 + l16;
        float bb = b2[col];
        #pragma unroll
        for (int r = 0; r < 4; ++r) {
            int row = quad * 4 + r;
            obuf[row][col] = acc3[nt][r] + bb + zbuf[row][col];
        }
    }
    __syncthreads();

    // LN2 + store (fp32)
    if (t < 256) {
        int row = t >> 4, j = t & 15;
        float s = 0.f, s2 = 0.f;
        #pragma unroll
        for (int i2 = 0; i2 < 16; ++i2) { float v = obuf[row][j + 16 * i2]; s += v; s2 += v * v; }
        red[row][j][0] = s; red[row][j][1] = s2;
    }
    __syncthreads();
    if (t < 16) {
        float s = 0.f, s2 = 0.f;
        #pragma unroll
        for (int j = 0; j < 16; ++j) { s += red[t][j][0]; s2 += red[t][j][1]; }
        float m = s * (1.f / 256.f);
        float var = s2 * (1.f / 256.f) - m * m;
        mrstd[t][0] = m;
        mrstd[t][1] = rsqrtf(var + 1e-5f);
    }
    __syncthreads();
    {
        int col = t & 255, rh = (t >> 8) * 8;
        float g = g2[col], be = be2[col];
        #pragma unroll
        for (int i2 = 0; i2 < 8; ++i2) {
            int row = rh + i2;
            out[(size_t)(b0 + row) * 256 + col] =
                (obuf[row][col] - mrstd[row][0]) * mrstd[row][1] * g + be;
        }
    }
}

// ---------------------------------------------------------------------------
extern "C" void kernel_launch(void* const* d_in, const int* in_sizes, int n_in,
                              void* d_out, int out_size, void* d_ws, size_t ws_size,
                              hipStream_t stream)
{
    (void)in_sizes; (void)n_in; (void)out_size; (void)ws_size;
    const float* xu    = (const float*)d_in[0];
    const float* x_ctx = (const float*)d_in[1];
    const float* t_ctx = (const float*)d_in[2];
    const float* freq  = (const float*)d_in[3];
    const float* phase = (const float*)d_in[4];
    const float* Wq    = (const float*)d_in[5];
    const float* Wk    = (const float*)d_in[6];
    const float* Wv    = (const float*)d_in[7];
    const float* Wres  = (const float*)d_in[8];
    const float* bres  = (const float*)d_in[9];
    const float* W1    = (const float*)d_in[10];
    const float* b1    = (const float*)d_in[11];
    const float* W2    = (const float*)d_in[12];
    const float* b2    = (const float*)d_in[13];
    const float* g1    = (const float*)d_in[14];
    const float* be1   = (const float*)d_in[15];
    const float* g2    = (const float*)d_in[16];
    const float* be2   = (const float*)d_in[17];
    float* out = (float*)d_out;

    char* ws = (char*)d_ws;
    u16* WcatT = (u16*)(ws);                    // 262,144 B
    u16* WresT = (u16*)(ws + 262144);           //  65,536
    u16* WvT   = (u16*)(ws + 327680);           // 131,072
    u16* W1T   = (u16*)(ws + 458752);           // 131,072
    u16* W2T   = (u16*)(ws + 589824);           // 131,072  (total 720,896 B)

    hipLaunchKernelGGL(k0_prep, dim3(1408), dim3(256), 0, stream,
                       Wq, Wk, Wv, Wres, W1, W2, WcatT, WresT, WvT, W1T, W2T);
    hipLaunchKernelGGL(kf_fused, dim3(1024), dim3(512), 0, stream,
                       xu, x_ctx, t_ctx, freq, phase,
                       WcatT, WvT, WresT, W1T, W2T,
                       bres, b1, b2, g1, be1, g2, be2, out);
}

// Round 7
// 487.570 us; speedup vs baseline: 1.1150x; 1.0888x over previous
//
#include <hip/hip_runtime.h>

typedef unsigned short u16;
typedef unsigned int   u32;

using bf16x8 = __attribute__((ext_vector_type(8))) short;
using f32x4  = __attribute__((ext_vector_type(4))) float;

#define MFMA16(A, B, C) __builtin_amdgcn_mfma_f32_16x16x32_bf16((A), (B), (C), 0, 0, 0)

static __device__ __forceinline__ u16 f2b(float f) {            // RNE
    u32 u = __builtin_bit_cast(u32, f);
    u32 r = (u + 0x7FFFu + ((u >> 16) & 1u)) >> 16;
    return (u16)r;
}
static __device__ __forceinline__ u16 f2bh(float f) {           // round-half-up
    u32 u = __builtin_bit_cast(u32, f) + 0x8000u;
    return (u16)(u >> 16);
}
// pack two floats -> two bf16 (half-up), a -> low16
static __device__ __forceinline__ u32 pk2(float fa, float fb) {
    u32 a = __builtin_bit_cast(u32, fa) + 0x8000u;
    u32 b = __builtin_bit_cast(u32, fb) + 0x8000u;
    return __builtin_amdgcn_perm(b, a, 0x07060302u);
}
static __device__ __forceinline__ bf16x8 cvt8f(f32x4 a, f32x4 b) {
    union { u32 w[4]; bf16x8 v; } r;
    r.w[0] = pk2(a[0], a[1]); r.w[1] = pk2(a[2], a[3]);
    r.w[2] = pk2(b[0], b[1]); r.w[3] = pk2(b[2], b[3]);
    return r.v;
}
static __device__ __forceinline__ bf16x8 cvt8(f32x4 a, f32x4 b) {   // RNE
    bf16x8 r;
    r[0] = (short)f2b(a[0]); r[1] = (short)f2b(a[1]);
    r[2] = (short)f2b(a[2]); r[3] = (short)f2b(a[3]);
    r[4] = (short)f2b(b[0]); r[5] = (short)f2b(b[1]);
    r[6] = (short)f2b(b[2]); r[7] = (short)f2b(b[3]);
    return r;
}

// ---------------------------------------------------------------------------
// K0: weight prep (fp32 -> bf16). Wcat dot vectorized (f32x4): 4x fewer
// load instructions, 16B/lane requests.
__global__ __launch_bounds__(256) void k0_prep(
    const float* __restrict__ Wq, const float* __restrict__ Wk,
    const float* __restrict__ Wv, const float* __restrict__ Wres,
    const float* __restrict__ W1, const float* __restrict__ W2,
    u16* __restrict__ WcatT, u16* __restrict__ WresT,
    u16* __restrict__ WvT, u16* __restrict__ W1T, u16* __restrict__ W2T)
{
    int t = blockIdx.x * 256 + threadIdx.x;
    if (t < 131072) {
        int n = t >> 7, i = t & 127;
        int h = n >> 8, c = n & 255;
        const f32x4* wq = (const f32x4*)(Wq + i * 256 + h * 64);
        const f32x4* wk = (const f32x4*)(Wk + c * 256 + h * 64);
        f32x4 a4 = {0.f, 0.f, 0.f, 0.f};
        #pragma unroll
        for (int d = 0; d < 16; ++d) a4 += wq[d] * wk[d];
        WcatT[t] = f2b((a4[0] + a4[1] + a4[2] + a4[3]) * 0.125f);
    } else if (t < 163840) {
        int o = t - 131072; int n = o >> 7, i = o & 127;
        WresT[o] = f2b(Wres[i * 256 + n]);
    } else if (t < 229376) {
        int o = t - 163840; int n = o >> 8, c = o & 255;
        WvT[o] = f2b(Wv[c * 256 + n]);
    } else if (t < 294912) {
        int o = t - 229376; int n = o >> 8, c = o & 255;
        W1T[o] = f2b(W1[c * 256 + n]);
    } else {
        int o = t - 294912; int n = o >> 8, c = o & 255;
        W2T[o] = f2b(W2[c * 256 + n]);
    }
}

// ---------------------------------------------------------------------------
// KF: fused qkvec-GEMM + attention + epilogue. 16 batch rows per block,
// 512 threads (8 waves), LDS 39552 B, __launch_bounds__(512,4) = the clean
// 128-reg tier (2 blocks/CU, 16 waves/CU — the only spill-free config;
// 64/85-reg tiers spill, R3/R5/R6).
//
// This round: hand software-pipelining at fixed occupancy. The kernel
// streams x_ctx at only 1.5 TB/s (19% peak) with 78% idle issue slots
// because loads are issued in short dependent bursts. Fix: explicit
// burst-loads + sched_barrier(0) fences, trig VALU moved into the load
// shadow:
//   attT: burst all 16 f32x4 x loads (both ltiles) -> fence -> te trig
//         fragments -> MFMA chains split into 2 independent accumulators.
//   PV:   2 halves x {burst 4nt scalar loads -> fence -> te trig (2 pp)
//         -> consume}.
// Spill watch: WRITE_SIZE ~16MB = clean; >50MB = halve bursts next round.
__global__ __launch_bounds__(512, 4) void kf_fused(
    const float* __restrict__ xu, const float* __restrict__ x_ctx,
    const float* __restrict__ t_ctx, const float* __restrict__ freq,
    const float* __restrict__ phase,
    const u16* __restrict__ WcatT, const u16* __restrict__ WvT,
    const u16* __restrict__ WresT, const u16* __restrict__ W1T,
    const u16* __restrict__ W2T,
    const float* __restrict__ bres, const float* __restrict__ b1,
    const float* __restrict__ b2, const float* __restrict__ g1,
    const float* __restrict__ be1, const float* __restrict__ g2,
    const float* __restrict__ be2, float* __restrict__ out)
{
    // layout:
    //   [    0,33024) kv[16][1032]  (u16)
    //   [33024,37376) xus[16][136]  (u16)
    //   [37376,39424) pw[8][4][32]  (u16)  | aliased by red[16][16][2] f32 (P3)
    //   [39424,39552) mrstd[16][2]  (f32)
    // P3 aliases of kv/xus region (xus dead once h1b/obuf tails reach it):
    //   zbuf[16][264] f32 @0      (16896)
    //   z1b [16][264] u16 @16896  (8448)
    //   h1b [16][264] u16 @25344  (8448, tail 768B into xus)
    //   obuf[16][264] f32 @16896  (16896)
    __shared__ __align__(16) char smem[39552];
    u16  (*kv)[1032]   = reinterpret_cast<u16 (*)[1032]>(smem);
    u16  (*xus)[136]   = reinterpret_cast<u16 (*)[136]>(smem + 33024);
    u16  (*pw)[4][32]  = reinterpret_cast<u16 (*)[4][32]>(smem + 37376);
    float(*red)[16][2] = reinterpret_cast<float (*)[16][2]>(smem + 37376); // alias pw
    float(*mrstd)[2]   = reinterpret_cast<float (*)[2]>(smem + 39424);
    float(*zbuf)[264]  = reinterpret_cast<float (*)[264]>(smem);           // alias kv
    u16  (*z1b)[264]   = reinterpret_cast<u16 (*)[264]>(smem + 16896);
    u16  (*h1b)[264]   = reinterpret_cast<u16 (*)[264]>(smem + 25344);
    float(*obuf)[264]  = reinterpret_cast<float (*)[264]>(smem + 16896);

    const int b0 = blockIdx.x * 16;
    const int t = threadIdx.x;
    const int lane = t & 63, wave = t >> 6;          // wave in [0,8)
    const int quad = lane >> 4, l16 = lane & 15;
    const int fb = quad * 8;
    const f32x4 zz = {0.f, 0.f, 0.f, 0.f};

    // ---- P0: stage x_u rows (bf16) ----
    if (t < 256) {
        int row = t >> 4, ch = t & 15;
        const float* src = xu + (size_t)(b0 + row) * 128 + ch * 8;
        *(bf16x8*)&xus[row][ch * 8] = cvt8(*(const f32x4*)src, *(const f32x4*)(src + 4));
    }
    __syncthreads();

    // ---- P1: kv[row][n] = qkvec = x_u @ Wcat (K=128); wave owns n-range w*128.. ----
    #pragma unroll 2
    for (int nt = 0; nt < 8; ++nt) {
        int n0 = wave * 128 + nt * 16;
        f32x4 acc = zz;
        #pragma unroll
        for (int ks = 0; ks < 4; ++ks) {
            bf16x8 afr = *(const bf16x8*)&xus[l16][ks * 32 + fb];
            bf16x8 bfr = *(const bf16x8*)(WcatT + (size_t)(n0 + l16) * 128 + ks * 32 + fb);
            acc = MFMA16(afr, bfr, acc);
        }
        #pragma unroll
        for (int r = 0; r < 4; ++r)
            kv[quad * 4 + r][n0 + l16] = f2b(acc[r]);
    }
    __syncthreads();

    // ---- P2: attention; wave w handles b = b0 + w*2 + i ----
    for (int i = 0; i < 2; ++i) {
        const int kvrow = wave * 2 + i;
        const int b = b0 + kvrow;
        float ltv = log1pf(fmaxf(t_ctx[(size_t)b * 32 + (lane & 31)], 0.f));
        const u16* qb = &kv[kvrow][(l16 & 3) * 256];

        // ---- attT burst: issue ALL 16 x_ctx f32x4 loads up-front (64 VGPRs
        // in flight; this is the HBM first-touch stream — max outstanding).
        f32x4 xa[2][4], xc[2][4];
        #pragma unroll
        for (int lt = 0; lt < 2; ++lt) {
            const float* xrow = x_ctx + ((size_t)b * 32 + lt * 16 + l16) * 128;
            #pragma unroll
            for (int ks = 0; ks < 4; ++ks) {
                xa[lt][ks] = *(const f32x4*)(xrow + ks * 32 + fb);
                xc[lt][ks] = *(const f32x4*)(xrow + ks * 32 + fb + 4);
            }
        }
        __builtin_amdgcn_sched_barrier(0);   // pin loads before the trig shadow

        // attT: D[l][h-replica], K=256; trig computed in the load shadow;
        // two independent MFMA accumulators (dep chain 8 -> 4).
        f32x4 accA[2];
        #pragma unroll
        for (int lt = 0; lt < 2; ++lt) {
            float lt_l = __shfl(ltv, lt * 16 + l16);
            bf16x8 te_s[2], te_c[2];
            #pragma unroll
            for (int hf = 0; hf < 2; ++hf) {
                f32x4 fa = *(const f32x4*)(freq + hf * 32 + fb);
                f32x4 fc = *(const f32x4*)(freq + hf * 32 + fb + 4);
                f32x4 pa = *(const f32x4*)(phase + hf * 32 + fb);
                f32x4 pc = *(const f32x4*)(phase + hf * 32 + fb + 4);
                f32x4 za = fa * lt_l + pa;
                f32x4 zc = fc * lt_l + pc;
                f32x4 sa, sc;
                #pragma unroll
                for (int j = 0; j < 4; ++j) { sa[j] = __sinf(za[j]); sc[j] = __sinf(zc[j]); }
                te_s[hf] = cvt8f(sa, sc);
                #pragma unroll
                for (int j = 0; j < 4; ++j) { sa[j] = __cosf(za[j]); sc[j] = __cosf(zc[j]); }
                te_c[hf] = cvt8f(sa, sc);
            }
            f32x4 a0 = zz, a1 = zz;
            a0 = MFMA16(cvt8f(xa[lt][0], xc[lt][0]), *(const bf16x8*)(qb + 0 * 32 + fb), a0);
            a1 = MFMA16(cvt8f(xa[lt][1], xc[lt][1]), *(const bf16x8*)(qb + 1 * 32 + fb), a1);
            a0 = MFMA16(cvt8f(xa[lt][2], xc[lt][2]), *(const bf16x8*)(qb + 2 * 32 + fb), a0);
            a1 = MFMA16(cvt8f(xa[lt][3], xc[lt][3]), *(const bf16x8*)(qb + 3 * 32 + fb), a1);
            a0 = MFMA16(te_s[0], *(const bf16x8*)(qb + 128 + fb), a0);
            a1 = MFMA16(te_s[1], *(const bf16x8*)(qb + 160 + fb), a1);
            a0 = MFMA16(te_c[0], *(const bf16x8*)(qb + 192 + fb), a0);
            a1 = MFMA16(te_c[1], *(const bf16x8*)(qb + 224 + fb), a1);
            accA[lt] = a0 + a1;
        }

        // softmax over l
        float m = accA[0][0];
        #pragma unroll
        for (int r = 1; r < 4; ++r) m = fmaxf(m, accA[0][r]);
        #pragma unroll
        for (int r = 0; r < 4; ++r) m = fmaxf(m, accA[1][r]);
        m = fmaxf(m, __shfl_xor(m, 16));
        m = fmaxf(m, __shfl_xor(m, 32));
        float p[2][4], s = 0.f;
        #pragma unroll
        for (int lt2 = 0; lt2 < 2; ++lt2)
            #pragma unroll
            for (int r = 0; r < 4; ++r) { p[lt2][r] = __expf(accA[lt2][r] - m); s += p[lt2][r]; }
        s += __shfl_xor(s, 16);
        s += __shfl_xor(s, 32);
        float inv = 1.f / s;
        if (l16 < 4) {
            #pragma unroll
            for (int lt2 = 0; lt2 < 2; ++lt2)
                #pragma unroll
                for (int r = 0; r < 4; ++r)
                    pw[wave][l16][lt2 * 16 + quad * 4 + r] = f2bh(p[lt2][r] * inv);
        }
        // no block barrier: pw is wave-private; lgkmcnt orders write->read.

        // PV: ctx[h][c] overwrites kv[kvrow] in place (row fully consumed above)
        bf16x8 pfr = *(const bf16x8*)&pw[wave][l16 & 3][fb];
        float ltj[8];
        #pragma unroll
        for (int j = 0; j < 8; ++j) ltj[j] = __shfl(ltv, fb + j);

        #pragma unroll
        for (int half = 0; half < 2; ++half) {
            // burst: 4 nt x 8 scalar L2 loads (32 VGPRs in flight)
            float xv[4][8];
            #pragma unroll
            for (int n4 = 0; n4 < 4; ++n4) {
                const float* xp = x_ctx + ((size_t)b * 32 + fb) * 128 + (half * 4 + n4) * 16 + l16;
                #pragma unroll
                for (int j = 0; j < 8; ++j) xv[n4][j] = xp[j * 128];
            }
            __builtin_amdgcn_sched_barrier(0);
            // te trig for 2 pp runs in the burst's shadow
            #pragma unroll
            for (int p2 = 0; p2 < 2; ++p2) {
                int f = (half * 2 + p2) * 16 + l16;
                float fq = freq[f], phf = phase[f];
                union { u32 w[4]; bf16x8 v; } bs, bc;
                #pragma unroll
                for (int j = 0; j < 4; ++j) {
                    float za = ltj[2 * j] * fq + phf;
                    float zb = ltj[2 * j + 1] * fq + phf;
                    bs.w[j] = pk2(__sinf(za), __sinf(zb));
                    bc.w[j] = pk2(__cosf(za), __cosf(zb));
                }
                f32x4 ds = MFMA16(pfr, bs.v, zz);
                f32x4 dc = MFMA16(pfr, bc.v, zz);
                if (quad == 0) {
                    #pragma unroll
                    for (int r = 0; r < 4; ++r) {
                        kv[kvrow][r * 256 + 128 + f] = f2bh(ds[r]);
                        kv[kvrow][r * 256 + 192 + f] = f2bh(dc[r]);
                    }
                }
            }
            // consume the x burst
            #pragma unroll
            for (int n4 = 0; n4 < 4; ++n4) {
                int c = (half * 4 + n4) * 16 + l16;
                union { u32 w[4]; bf16x8 v; } bu;
                bu.w[0] = pk2(xv[n4][0], xv[n4][1]); bu.w[1] = pk2(xv[n4][2], xv[n4][3]);
                bu.w[2] = pk2(xv[n4][4], xv[n4][5]); bu.w[3] = pk2(xv[n4][6], xv[n4][7]);
                f32x4 d = MFMA16(pfr, bu.v, zz);
                if (quad == 0) {
                    #pragma unroll
                    for (int r = 0; r < 4; ++r) kv[kvrow][r * 256 + c] = f2bh(d[r]);
                }
            }
        }
    }
    __syncthreads();

    // ---- P3: epilogue. Wave owns 32 output cols; head = wave>>1. ----
    const int nw = wave * 32;
    const int hd = (wave >> 1) * 256;

    // Phase A: agg = ctx_head @ Wv + xu @ Wres + bres
    f32x4 acc[2];
    #pragma unroll
    for (int nt = 0; nt < 2; ++nt) acc[nt] = zz;
    #pragma unroll
    for (int ks = 0; ks < 8; ++ks) {
        bf16x8 afr = *(const bf16x8*)&kv[l16][hd + ks * 32 + quad * 8];
        #pragma unroll
        for (int nt = 0; nt < 2; ++nt) {
            bf16x8 bfr = *(const bf16x8*)(WvT + (size_t)(nw + nt * 16 + l16) * 256 + ks * 32 + quad * 8);
            acc[nt] = MFMA16(afr, bfr, acc[nt]);
        }
    }
    #pragma unroll
    for (int ks = 0; ks < 4; ++ks) {
        bf16x8 afr = *(const bf16x8*)&xus[l16][ks * 32 + quad * 8];
        #pragma unroll
        for (int nt = 0; nt < 2; ++nt) {
            bf16x8 bfr = *(const bf16x8*)(WresT + (size_t)(nw + nt * 16 + l16) * 128 + ks * 32 + quad * 8);
            acc[nt] = MFMA16(afr, bfr, acc[nt]);
        }
    }
    __syncthreads();                               // kv/xus dead
    #pragma unroll
    for (int nt = 0; nt < 2; ++nt) {
        int col = nw + nt * 16 + l16;
        float bb = bres[col];
        #pragma unroll
        for (int r = 0; r < 4; ++r)
            zbuf[quad * 4 + r][col] = acc[nt][r] + bb;
    }
    __syncthreads();

    // LN1
    if (t < 256) {
        int row = t >> 4, j = t & 15;
        float s = 0.f, s2 = 0.f;
        #pragma unroll
        for (int i2 = 0; i2 < 16; ++i2) { float v = zbuf[row][j + 16 * i2]; s += v; s2 += v * v; }
        red[row][j][0] = s; red[row][j][1] = s2;
    }
    __syncthreads();
    if (t < 16) {
        float s = 0.f, s2 = 0.f;
        #pragma unroll
        for (int j = 0; j < 16; ++j) { s += red[t][j][0]; s2 += red[t][j][1]; }
        float m = s * (1.f / 256.f);
        float var = s2 * (1.f / 256.f) - m * m;
        mrstd[t][0] = m;
        mrstd[t][1] = rsqrtf(var + 1e-5f);
    }
    __syncthreads();
    {
        int col = t & 255, rh = (t >> 8) * 8;
        float g = g1[col], be = be1[col];
        #pragma unroll
        for (int i2 = 0; i2 < 8; ++i2) {
            int row = rh + i2;
            float z = (zbuf[row][col] - mrstd[row][0]) * mrstd[row][1] * g + be;
            zbuf[row][col] = z;
            z1b[row][col] = f2b(z);
        }
    }
    __syncthreads();

    // Phase B: FFN1 + relu
    f32x4 acc2[2];
    #pragma unroll
    for (int nt = 0; nt < 2; ++nt) acc2[nt] = zz;
    #pragma unroll
    for (int ks = 0; ks < 8; ++ks) {
        bf16x8 afr = *(const bf16x8*)&z1b[l16][ks * 32 + quad * 8];
        #pragma unroll
        for (int nt = 0; nt < 2; ++nt) {
            bf16x8 bfr = *(const bf16x8*)(W1T + (size_t)(nw + nt * 16 + l16) * 256 + ks * 32 + quad * 8);
            acc2[nt] = MFMA16(afr, bfr, acc2[nt]);
        }
    }
    #pragma unroll
    for (int nt = 0; nt < 2; ++nt) {
        int col = nw + nt * 16 + l16;
        float bb = b1[col];
        #pragma unroll
        for (int r = 0; r < 4; ++r)
            h1b[quad * 4 + r][col] = f2b(fmaxf(acc2[nt][r] + bb, 0.f));
    }
    __syncthreads();

    // Phase C: FFN2 + residual
    f32x4 acc3[2];
    #pragma unroll
    for (int nt = 0; nt < 2; ++nt) acc3[nt] = zz;
    #pragma unroll
    for (int ks = 0; ks < 8; ++ks) {
        bf16x8 afr = *(const bf16x8*)&h1b[l16][ks * 32 + quad * 8];
        #pragma unroll
        for (int nt = 0; nt < 2; ++nt) {
            bf16x8 bfr = *(const bf16x8*)(W2T + (size_t)(nw + nt * 16 + l16) * 256 + ks * 32 + quad * 8);
            acc3[nt] = MFMA16(afr, bfr, acc3[nt]);
        }
    }
    __syncthreads();                               // z1b/h1b dead
    #pragma unroll
    for (int nt = 0; nt < 2; ++nt) {
        int col = nw + nt * 16 + l16;
        float bb = b2[col];
        #pragma unroll
        for (int r = 0; r < 4; ++r) {
            int row = quad * 4 + r;
            obuf[row][col] = acc3[nt][r] + bb + zbuf[row][col];
        }
    }
    __syncthreads();

    // LN2 + store (fp32)
    if (t < 256) {
        int row = t >> 4, j = t & 15;
        float s = 0.f, s2 = 0.f;
        #pragma unroll
        for (int i2 = 0; i2 < 16; ++i2) { float v = obuf[row][j + 16 * i2]; s += v; s2 += v * v; }
        red[row][j][0] = s; red[row][j][1] = s2;
    }
    __syncthreads();
    if (t < 16) {
        float s = 0.f, s2 = 0.f;
        #pragma unroll
        for (int j = 0; j < 16; ++j) { s += red[t][j][0]; s2 += red[t][j][1]; }
        float m = s * (1.f / 256.f);
        float var = s2 * (1.f / 256.f) - m * m;
        mrstd[t][0] = m;
        mrstd[t][1] = rsqrtf(var + 1e-5f);
    }
    __syncthreads();
    {
        int col = t & 255, rh = (t >> 8) * 8;
        float g = g2[col], be = be2[col];
        #pragma unroll
        for (int i2 = 0; i2 < 8; ++i2) {
            int row = rh + i2;
            out[(size_t)(b0 + row) * 256 + col] =
                (obuf[row][col] - mrstd[row][0]) * mrstd[row][1] * g + be;
        }
    }
}

// ---------------------------------------------------------------------------
extern "C" void kernel_launch(void* const* d_in, const int* in_sizes, int n_in,
                              void* d_out, int out_size, void* d_ws, size_t ws_size,
                              hipStream_t stream)
{
    (void)in_sizes; (void)n_in; (void)out_size; (void)ws_size;
    const float* xu    = (const float*)d_in[0];
    const float* x_ctx = (const float*)d_in[1];
    const float* t_ctx = (const float*)d_in[2];
    const float* freq  = (const float*)d_in[3];
    const float* phase = (const float*)d_in[4];
    const float* Wq    = (const float*)d_in[5];
    const float* Wk    = (const float*)d_in[6];
    const float* Wv    = (const float*)d_in[7];
    const float* Wres  = (const float*)d_in[8];
    const float* bres  = (const float*)d_in[9];
    const float* W1    = (const float*)d_in[10];
    const float* b1    = (const float*)d_in[11];
    const float* W2    = (const float*)d_in[12];
    const float* b2    = (const float*)d_in[13];
    const float* g1    = (const float*)d_in[14];
    const float* be1   = (const float*)d_in[15];
    const float* g2    = (const float*)d_in[16];
    const float* be2   = (const float*)d_in[17];
    float* out = (float*)d_out;

    char* ws = (char*)d_ws;
    u16* WcatT = (u16*)(ws);                    // 262,144 B
    u16* WresT = (u16*)(ws + 262144);           //  65,536
    u16* WvT   = (u16*)(ws + 327680);           // 131,072
    u16* W1T   = (u16*)(ws + 458752);           // 131,072
    u16* W2T   = (u16*)(ws + 589824);           // 131,072  (total 720,896 B)

    hipLaunchKernelGGL(k0_prep, dim3(1408), dim3(256), 0, stream,
                       Wq, Wk, Wv, Wres, W1, W2, WcatT, WresT, WvT, W1T, W2T);
    hipLaunchKernelGGL(kf_fused, dim3(1024), dim3(512), 0, stream,
                       xu, x_ctx, t_ctx, freq, phase,
                       WcatT, WvT, WresT, W1T, W2T,
                       bres, b1, b2, g1, be1, g2, be2, out);
}